// Round 10
// baseline (235.536 us; speedup 1.0000x reference)
//
#include <hip/hip_runtime.h>

constexpr int NKD = 64;    // node key dim
constexpr int EKD = 16;    // edge key dim
constexpr int QD  = 80;    // NKD + EKD
constexpr int NN  = 256;   // sequence length
constexpr int DVD = 64;    // value dim
constexpr int BB  = 4;
constexpr int HH  = 8;
constexpr int QT  = 8;     // q rows per block (k2)
constexpr int K1QT = 32;   // q rows per block (k1)

// ---------- kernel 1: node scores (+mask, +1/T scale) -> attn region of d_out ----------
// S0 is staged in the attn output region (same size, 8.4 MB); k2 overwrites it
// with the final attn tile-locally AFTER reading its S0 tile. No d_ws needed.
// Grid: 32 bh x 8 tiles = 256 blocks, 256 threads. Thread = key k; its nk row
// lives in 16 float4 regs, amortized over 32 q rows.
__global__ __launch_bounds__(256) void node_score_kernel(
    const float* __restrict__ q, const float* __restrict__ nk,
    const int* __restrict__ mask, float* __restrict__ s0)
{
    const int bid = blockIdx.x;
    const int bh  = bid >> 3;
    const int q0  = (bid & 7) * K1QT;
    const int b   = bh >> 3;             // H == 8
    const int tid = threadIdx.x;         // k

    __shared__ float4 s_qn[K1QT * 16];   // 32 rows x 64 node dims (8 KB)

    {
        const float4* qsrc = (const float4*)(q + ((size_t)bh * NN + q0) * QD);
        #pragma unroll
        for (int i = tid; i < K1QT * 16; i += 256) {
            const int r = i >> 4, j = i & 15;
            s_qn[i] = qsrc[r * 20 + j];          // first 64 of 80 dims
        }
    }
    float4 nkr[16];
    {
        const float4* nkp = (const float4*)(nk + ((size_t)bh * NN + tid) * NKD);
        #pragma unroll
        for (int j = 0; j < 16; ++j) nkr[j] = nkp[j];
    }
    __syncthreads();

    float*     dst  = s0   + ((size_t)bh * NN + q0) * NN + tid;
    const int* mrow = mask + ((size_t)b  * NN + q0) * NN + tid;
    #pragma unroll 4
    for (int r = 0; r < K1QT; ++r) {
        float acc = 0.f;
        #pragma unroll
        for (int j = 0; j < 16; ++j) {
            const float4 a = s_qn[r * 16 + j], n = nkr[j];
            acc += a.x * n.x + a.y * n.y + a.z * n.z + a.w * n.w;
        }
        acc *= 0.125f;
        if (mrow[(size_t)r * NN] == 0) acc = -1.0e9f;
        dst[(size_t)r * NN] = acc;
    }
}

// ---------- kernel 2: edge scores + softmax + PV ----------
// Grid: 32 bh x 32 q-tiles = 1024 blocks (4/CU), 256 threads (4 waves).
// s0 aliases attn_out: each block reads ONLY its own tile (before any write)
// and overwrites ONLY its own tile after __syncthreads — no cross-block hazard.
__global__ __launch_bounds__(256) void sdpe_kernel(
    const float* __restrict__ q, const float* __restrict__ s0,
    const float* __restrict__ ek, const float* __restrict__ v,
    float* __restrict__ out, float* __restrict__ attn_out)
{
    const int bid  = blockIdx.x;
    const int bh   = bid >> 5;
    const int q0   = (bid & 31) * QT;
    const int tid  = threadIdx.x;
    const int wave = tid >> 6;
    const int lane = tid & 63;

    __shared__ float  s_S[QT * NN];          // 8 KB  scores -> attn in place
    __shared__ float4 s_qe[QT * 4];          // 8 rows x 16 edge dims
    __shared__ float4 s_part[4][QT][16];     // 8 KB  PV partials per wave

    // ---- stage S0 tile (coalesced f4 stream) + qe ----
    {
        const float4* ssrc = (const float4*)(s0 + ((size_t)bh * NN + q0) * NN);
        float4* sdst = (float4*)s_S;
        sdst[tid]       = ssrc[tid];
        sdst[tid + 256] = ssrc[tid + 256];
        if (tid < QT * 4) {
            const int r = tid >> 2, j = tid & 3;
            s_qe[tid] = *(const float4*)(q + ((size_t)bh * NN + q0 + r) * QD + NKD + j * 4);
        }
    }
    __syncthreads();

    // ---- edge scores: flat contiguous float4 stream (134 MB, read once) ----
    // thread t: jb = t&3 (edge-dim quarter), kb = t>>2; covers k = kb + 64*i.
    {
        const int jb = tid & 3;
        const int kb = tid >> 2;
        const float4* ekb = (const float4*)ek + ((size_t)bh * NN + q0) * (NN * EKD / 4);
        #pragma unroll 2
        for (int r = 0; r < QT; ++r) {
            const float4 qe4 = s_qe[r * 4 + jb];
            const float4 e0 = ekb[(size_t)r * 1024 + tid];
            const float4 e1 = ekb[(size_t)r * 1024 + tid + 256];
            const float4 e2 = ekb[(size_t)r * 1024 + tid + 512];
            const float4 e3 = ekb[(size_t)r * 1024 + tid + 768];
            float p0 = e0.x*qe4.x + e0.y*qe4.y + e0.z*qe4.z + e0.w*qe4.w;
            float p1 = e1.x*qe4.x + e1.y*qe4.y + e1.z*qe4.z + e1.w*qe4.w;
            float p2 = e2.x*qe4.x + e2.y*qe4.y + e2.z*qe4.z + e2.w*qe4.w;
            float p3 = e3.x*qe4.x + e3.y*qe4.y + e3.z*qe4.z + e3.w*qe4.w;
            p0 += __shfl_xor(p0, 1);  p0 += __shfl_xor(p0, 2);
            p1 += __shfl_xor(p1, 1);  p1 += __shfl_xor(p1, 2);
            p2 += __shfl_xor(p2, 1);  p2 += __shfl_xor(p2, 2);
            p3 += __shfl_xor(p3, 1);  p3 += __shfl_xor(p3, 2);
            const float pw = (jb == 0) ? p0 : (jb == 1) ? p1 : (jb == 2) ? p2 : p3;
            s_S[r * NN + kb + 64 * jb] += 0.125f * pw;
        }
    }
    __syncthreads();

    // ---- softmax: wave w handles rows {w, w+4} (mask/scale already in S0) ----
    #pragma unroll
    for (int rr = 0; rr < 2; ++rr) {
        const int r = wave + rr * 4;
        const size_t rowg = (size_t)bh * NN + q0 + r;
        float4 f = *(const float4*)&s_S[r * NN + lane * 4];
        float mx = fmaxf(fmaxf(f.x, f.y), fmaxf(f.z, f.w));
        #pragma unroll
        for (int o = 32; o >= 1; o >>= 1) mx = fmaxf(mx, __shfl_xor(mx, o));
        float4 e;
        e.x = __expf(f.x - mx); e.y = __expf(f.y - mx);
        e.z = __expf(f.z - mx); e.w = __expf(f.w - mx);
        float s = e.x + e.y + e.z + e.w;
        #pragma unroll
        for (int o = 32; o >= 1; o >>= 1) s += __shfl_xor(s, o);
        const float inv = 1.f / s;
        e.x *= inv; e.y *= inv; e.z *= inv; e.w *= inv;
        *(float4*)&s_S[r * NN + lane * 4] = e;
        *(float4*)(attn_out + rowg * NN + lane * 4) = e;   // overwrites own S0 tile
    }
    __syncthreads();

    // ---- PV: wave w owns k in [64w, 64w+64); lane = (kq, d4). v read ONCE/block.
    {
        const int d4 = lane & 15;
        const int kq = lane >> 4;
        float4 acc[QT];
        #pragma unroll
        for (int r = 0; r < QT; ++r) acc[r] = make_float4(0.f, 0.f, 0.f, 0.f);

        const float* vb = v + (size_t)bh * NN * DVD + d4 * 4;
        #pragma unroll
        for (int i = 0; i < 4; ++i) {
            const int k0 = wave * 64 + i * 16 + kq * 4;
            const float4 v0 = *(const float4*)(vb + (size_t)(k0 + 0) * DVD);
            const float4 v1 = *(const float4*)(vb + (size_t)(k0 + 1) * DVD);
            const float4 v2 = *(const float4*)(vb + (size_t)(k0 + 2) * DVD);
            const float4 v3 = *(const float4*)(vb + (size_t)(k0 + 3) * DVD);
            #pragma unroll
            for (int r = 0; r < QT; ++r) {
                const float4 a4 = *(const float4*)&s_S[r * NN + k0];  // 16-lane bcast
                acc[r].x += a4.x*v0.x + a4.y*v1.x + a4.z*v2.x + a4.w*v3.x;
                acc[r].y += a4.x*v0.y + a4.y*v1.y + a4.z*v2.y + a4.w*v3.y;
                acc[r].z += a4.x*v0.z + a4.y*v1.z + a4.z*v2.z + a4.w*v3.z;
                acc[r].w += a4.x*v0.w + a4.y*v1.w + a4.z*v2.w + a4.w*v3.w;
            }
        }
        #pragma unroll
        for (int r = 0; r < QT; ++r) {
            acc[r].x += __shfl_xor(acc[r].x, 16); acc[r].y += __shfl_xor(acc[r].y, 16);
            acc[r].z += __shfl_xor(acc[r].z, 16); acc[r].w += __shfl_xor(acc[r].w, 16);
            acc[r].x += __shfl_xor(acc[r].x, 32); acc[r].y += __shfl_xor(acc[r].y, 32);
            acc[r].z += __shfl_xor(acc[r].z, 32); acc[r].w += __shfl_xor(acc[r].w, 32);
            if (kq == 0) s_part[wave][r][d4] = acc[r];
        }
    }
    __syncthreads();

    if (tid < QT * 16) {
        const int r = tid >> 4, d4 = tid & 15;
        const float4 p0 = s_part[0][r][d4], p1 = s_part[1][r][d4];
        const float4 p2 = s_part[2][r][d4], p3 = s_part[3][r][d4];
        float4 o;
        o.x = p0.x + p1.x + p2.x + p3.x;
        o.y = p0.y + p1.y + p2.y + p3.y;
        o.z = p0.z + p1.z + p2.z + p3.z;
        o.w = p0.w + p1.w + p2.w + p3.w;
        const size_t rowg = (size_t)bh * NN + q0 + r;
        *(float4*)(out + rowg * DVD + d4 * 4) = o;
    }
}

extern "C" void kernel_launch(void* const* d_in, const int* in_sizes, int n_in,
                              void* d_out, int out_size, void* d_ws, size_t ws_size,
                              hipStream_t stream) {
    const float* q    = (const float*)d_in[0];
    const float* nk   = (const float*)d_in[1];
    const float* ek   = (const float*)d_in[2];
    const float* v    = (const float*)d_in[3];
    const int*   mask = (const int*)d_in[4];

    float* out      = (float*)d_out;
    float* attn_out = out + (size_t)BB * HH * NN * DVD;   // tuple: (output, attn)

    // S0 staged in the attn region itself (same 8.4 MB footprint; k2 reads its
    // tile before overwriting it). No d_ws usage -> no ws_size assumptions.
    node_score_kernel<<<BB * HH * (NN / K1QT), 256, 0, stream>>>(q, nk, mask, attn_out);
    sdpe_kernel<<<BB * HH * (NN / QT), 256, 0, stream>>>(q, attn_out, ek, v, out, attn_out);
}